// Round 16
// baseline (1138.362 us; speedup 1.0000x reference)
//
#include <hip/hip_runtime.h>
#include <stdint.h>

#define ATOM_FDIM 133
#define BOND_FDIM 147
#define HIDDEN    300
#define N_ATOMS   100000
#define N_BONDS   200000
#define MAX_NB    6
#define N_MOLS    4000

#define KP_I 160      // padded K for W_i GEMM (147)
#define KP_H 320      // padded K for W_h GEMM (300)
#define KP_O 448      // padded K for output GEMM (433, reordered amsg|f_atoms|0)
#define LDA  304      // activation row stride in elems (608B, 16B-aligned)
#define CPR  38       // uint4 chunks per activation row (304/8)

#define TM   256      // GEMM tile rows (16 waves x 16 rows)
#define BCH  20       // B chunks (1KB) per K32 tile (NPAD = 320)

typedef unsigned short u16;
typedef short bf16x8 __attribute__((ext_vector_type(8)));
typedef float f32x4 __attribute__((ext_vector_type(4)));

__device__ __forceinline__ u16 f2bu(float f) {            // f32 -> bf16 (RNE)
    unsigned u = __float_as_uint(f);
    u += 0x7FFFu + ((u >> 16) & 1u);
    return (u16)(u >> 16);
}
__device__ __forceinline__ float bu2f(u16 b) { return __uint_as_float(((unsigned)b) << 16); }

__device__ __forceinline__ uint4 relu_bf16x8(uint4 v) {
    union { uint4 u; u16 s[8]; } x, o;
    x.u = v;
    #pragma unroll
    for (int e = 0; e < 8; ++e) o.s[e] = (x.s[e] & 0x8000u) ? (u16)0 : x.s[e];
    return o.u;
}
__device__ __forceinline__ uint4 comb_bf16x8(uint4 vi, uint4 va, uint4 vy) {
    union { uint4 u; u16 s[8]; } xi, xa, xy, o;
    xi.u = vi; xa.u = va; xy.u = vy;
    #pragma unroll
    for (int e = 0; e < 8; ++e)
        o.s[e] = f2bu(fmaxf(bu2f(xi.s[e]) + bu2f(xa.s[e]) - bu2f(xy.s[e]), 0.f));
    return o.u;
}

#define AS1 __attribute__((address_space(1)))
#define AS3 __attribute__((address_space(3)))
__device__ __forceinline__ void gl_lds(const void* g, void* l) {
    __builtin_amdgcn_global_load_lds((const AS1 void*)g, (AS3 void*)l, 16, 0, 0);
}
#define MFMA(a, b, c) __builtin_amdgcn_mfma_f32_16x16x32_bf16((a), (b), (c), 0, 0, 0)

// ---------- dense-A bf16 MFMA GEMM: 1024 threads, 16 waves, 256x320 tile ----------
// 16 waves as 8x2; wave = 32 rows x 160 cols = 2x10 frags of 16x16x32.
// LDS: A tri 3x16KB + B tri 3x20KB = 108KB -> 16 waves/CU (2x the 512-thr version;
// achieved HBM BW scales with resident waves: aggcat @78% occ hits 3.1 TB/s vs
// GEMM @20% occ 2.3 TB/s). Stage t+2 (A chunk wid; B chunk wid + [wid<4] chunk
// 16+wid). Gates wave-uniform literal: wid<4 vmcnt(3), else vmcnt(2) -- retires
// t+1's stages, never drains t+2. EPI 1: raw | 2: relu(v+bias)
template <int EPI>
__global__ __launch_bounds__(1024) void mm_k(
    const u16* __restrict__ A, int lda,
    const u16* __restrict__ Wp,          // panel layout: [NT][BCH][512]
    const float* __restrict__ bias,
    u16* __restrict__ out0, int ldo0,
    int M, int NT)                       // NT = Kp/32 >= 3
{
    __shared__ __align__(16) u16 As[3][16 * 512];   // 3 x 16 KB
    __shared__ __align__(16) u16 Bs[3][20 * 512];   // 3 x 20 KB

    const int t    = threadIdx.x;
    const int lane = t & 63, wid = t >> 6;          // wid 0..15
    const int fl   = lane & 15, fh = lane >> 4;
    const int m0   = blockIdx.x * TM;
    const int wr   = wid >> 1, wc = wid & 1;

    int arow = m0 + wid * 16 + fl;
    if (arow > M - 1) arow = M - 1;
    const char* srcAp = (const char*)A + (size_t)arow * (size_t)lda * 2u + (size_t)(fh * 16);
    const char* WpC = (const char*)Wp;
    const size_t srcB0 = (size_t)wid * 1024u + (size_t)lane * 16u;
    const size_t srcB1 = (size_t)(16 + wid) * 1024u + (size_t)lane * 16u;

    f32x4 acc[2][10] = {};

#define STAGE_T(kt, buf) do {                                                      \
        const size_t kb_ = (size_t)(kt) * (size_t)(BCH * 1024);                    \
        gl_lds(srcAp + (size_t)(kt) * 64u, (char*)As[buf] + wid * 1024);           \
        gl_lds(WpC + kb_ + srcB0, (char*)Bs[buf] + wid * 1024);                    \
        if (wid < 4)                                                               \
            gl_lds(WpC + kb_ + srcB1, (char*)Bs[buf] + (16 + wid) * 1024);         \
    } while (0)

#define GATE() do {                                                        \
        if (wid < 4) asm volatile("s_waitcnt vmcnt(3)" ::: "memory");      \
        else         asm volatile("s_waitcnt vmcnt(2)" ::: "memory");      \
    } while (0)

    STAGE_T(0, 0);
    STAGE_T(1, 1);
    GATE();
    __builtin_amdgcn_s_barrier();

    int cur = 0;
    for (int tt = 0; tt < NT; ++tt) {
        int w2 = tt + 2; if (w2 >= NT) w2 -= NT;
        const int nx1 = (cur < 2) ? cur + 1 : 0;
        const int nx2 = (nx1 < 2) ? nx1 + 1 : 0;
        const u16* as_c = As[cur];
        const u16* bs_c = Bs[cur];

        bf16x8 af0, af1, bfv[10];
        // ---------- phase 1 ----------
        af0 = *reinterpret_cast<const bf16x8*>(&as_c[(wr * 2 + 0) * 512 + lane * 8]);
        af1 = *reinterpret_cast<const bf16x8*>(&as_c[(wr * 2 + 1) * 512 + lane * 8]);
        #pragma unroll
        for (int n = 0; n < 5; ++n)
            bfv[n] = *reinterpret_cast<const bf16x8*>(&bs_c[(wc * 10 + n) * 512 + lane * 8]);
        STAGE_T(w2, nx2);
        __builtin_amdgcn_s_barrier();
        __builtin_amdgcn_s_setprio(1);
        #pragma unroll
        for (int n = 0; n < 5; ++n) {
            acc[0][n] = MFMA(af0, bfv[n], acc[0][n]);
            acc[1][n] = MFMA(af1, bfv[n], acc[1][n]);
        }
        __builtin_amdgcn_s_setprio(0);
        __builtin_amdgcn_s_barrier();

        // ---------- phase 2 ----------
        #pragma unroll
        for (int n = 5; n < 10; ++n)
            bfv[n] = *reinterpret_cast<const bf16x8*>(&bs_c[(wc * 10 + n) * 512 + lane * 8]);
        GATE();                                   // retire tile t+1's stages only
        __builtin_amdgcn_s_barrier();
        __builtin_amdgcn_s_setprio(1);
        #pragma unroll
        for (int n = 5; n < 10; ++n) {
            acc[0][n] = MFMA(af0, bfv[n], acc[0][n]);
            acc[1][n] = MFMA(af1, bfv[n], acc[1][n]);
        }
        __builtin_amdgcn_s_setprio(0);
        __builtin_amdgcn_s_barrier();
        cur = nx1;
    }
#undef STAGE_T
#undef GATE

    #pragma unroll
    for (int m = 0; m < 2; ++m) {
        #pragma unroll
        for (int r = 0; r < 4; ++r) {
            const int row = m0 + wr * 32 + m * 16 + fh * 4 + r;
            if (row >= M) continue;
            #pragma unroll
            for (int n = 0; n < 10; ++n) {
                const int col = wc * 160 + n * 16 + fl;
                if (col >= HIDDEN) continue;
                const float v = acc[m][n][r];
                if (EPI == 1) out0[(size_t)row * ldo0 + col] = f2bu(v);
                else          out0[(size_t)row * ldo0 + col] = f2bu(fmaxf(v + bias[col], 0.f));
            }
        }
    }
}

// ---------- fused-A bf16 MFMA GEMM: 1024 threads, 16 waves, reg-staged A ----------
// AM1: A' = relu(inp) | AM2: A' = relu(inp + aY[b2a] - Y[b2revb]). Raw out.
// LDS: A dbuf 2x16KB + B tri 3x20KB = 92KB. Per tile each lane loads 1-3 uint4
// (t+2), transforms + 1 ds_write (t+1) after the counted gate. B staged t+2 via
// gl_lds (rotation). Gates: AM1 wid<4 vmcnt(3)/else 2; AM2 5/4. Never drains.
template <int AM>
__global__ __launch_bounds__(1024) void mmf_k(
    const u16* __restrict__ A, int lda,          // inp
    const u16* __restrict__ aYp,                 // AM2
    const u16* __restrict__ Yp,                  // AM2
    const int* __restrict__ b2a,                 // AM2
    const int* __restrict__ b2revb,              // AM2
    const u16* __restrict__ Wp,
    u16* __restrict__ out0, int ldo0,
    int M, int NT)                               // NT = Kp/32 >= 2
{
    __shared__ __align__(16) u16 As[2][16 * 512];   // 2 x 16 KB
    __shared__ __align__(16) u16 Bs[3][20 * 512];   // 3 x 20 KB

    const int t    = threadIdx.x;
    const int lane = t & 63, wid = t >> 6;
    const int fl   = lane & 15, fh = lane >> 4;
    const int m0   = blockIdx.x * TM;
    const int wr   = wid >> 1, wc = wid & 1;

    int arow = m0 + wid * 16 + fl;
    if (arow > M - 1) arow = M - 1;
    const char* pI = (const char*)A + (size_t)arow * (size_t)lda * 2u + (size_t)(fh * 16);
    const char* pA = nullptr; const char* pY = nullptr;
    if constexpr (AM == 2) {
        const int ia = b2a[arow], ir = b2revb[arow];
        pA = (const char*)aYp + (size_t)ia * (LDA * 2) + (size_t)(fh * 16);
        pY = (const char*)Yp  + (size_t)ir * (LDA * 2) + (size_t)(fh * 16);
    }
    const char* WpC = (const char*)Wp;
    const size_t srcB0 = (size_t)wid * 1024u + (size_t)lane * 16u;
    const size_t srcB1 = (size_t)(16 + wid) * 1024u + (size_t)lane * 16u;

    f32x4 acc[2][10] = {};
    uint4 Xi, Xa, Xy, Yi, Ya, Yy;
    (void)Xa; (void)Xy; (void)Ya; (void)Yy;

#define STAGE_B(kt, buf) do {                                                      \
        const size_t kb_ = (size_t)(kt) * (size_t)(BCH * 1024);                    \
        gl_lds(WpC + kb_ + srcB0, (char*)Bs[buf] + wid * 1024);                    \
        if (wid < 4)                                                               \
            gl_lds(WpC + kb_ + srcB1, (char*)Bs[buf] + (16 + wid) * 1024);         \
    } while (0)
#define LOADSET(kt, I0, A0, Y0) do {                                               \
        const size_t kb_ = (size_t)(kt) * 64u;                                     \
        I0 = *reinterpret_cast<const uint4*>(pI + kb_);                            \
        if constexpr (AM == 2) {                                                   \
            A0 = *reinterpret_cast<const uint4*>(pA + kb_);                        \
            Y0 = *reinterpret_cast<const uint4*>(pY + kb_);                        \
        }                                                                          \
    } while (0)
#define XF(I, Aa, Yy) (AM == 2 ? comb_bf16x8(I, Aa, Yy) : relu_bf16x8(I))
#define GATE() do {                                                        \
    if constexpr (AM == 2) {                                               \
        if (wid < 4) asm volatile("s_waitcnt vmcnt(5)" ::: "memory");      \
        else         asm volatile("s_waitcnt vmcnt(4)" ::: "memory");      \
    } else {                                                               \
        if (wid < 4) asm volatile("s_waitcnt vmcnt(3)" ::: "memory");      \
        else         asm volatile("s_waitcnt vmcnt(2)" ::: "memory");      \
    } } while (0)

    // ---- prologue: X<-L(0); B(0); Y<-L(1); B(1); wait X; write A(0); wait B(0) ----
    LOADSET(0, Xi, Xa, Xy);
    STAGE_B(0, 0);
    LOADSET(1, Yi, Ya, Yy);
    STAGE_B(1, 1);
    if constexpr (AM == 2) {
        if (wid < 4) asm volatile("s_waitcnt vmcnt(7)" ::: "memory");
        else         asm volatile("s_waitcnt vmcnt(5)" ::: "memory");
    } else {
        if (wid < 4) asm volatile("s_waitcnt vmcnt(5)" ::: "memory");
        else         asm volatile("s_waitcnt vmcnt(3)" ::: "memory");
    }
    *reinterpret_cast<uint4*>(&As[0][wid * 512 + lane * 8]) = XF(Xi, Xa, Xy);
    GATE();   // B(0) landed; keep L(1)+B(1)
    asm volatile("s_waitcnt lgkmcnt(0)" ::: "memory");
    __builtin_amdgcn_s_barrier();

    int tt = 0, bcur = 0;

#define STEP(LI, LA, LY, WI, WA, WY) do {                                                   \
    int w2 = tt + 2; if (w2 >= NT) w2 -= NT;                                                \
    const u16* as_c = As[tt & 1];                                                           \
    const u16* bs_c = Bs[bcur];                                                             \
    int bnx = bcur + 2; if (bnx >= 3) bnx -= 3;                                             \
    bf16x8 af0, af1, bfv[10];                                                               \
    /* phase 1 */                                                                           \
    af0 = *reinterpret_cast<const bf16x8*>(&as_c[(wr * 2 + 0) * 512 + lane * 8]);           \
    af1 = *reinterpret_cast<const bf16x8*>(&as_c[(wr * 2 + 1) * 512 + lane * 8]);           \
    _Pragma("unroll")                                                                       \
    for (int n = 0; n < 5; ++n)                                                             \
        bfv[n] = *reinterpret_cast<const bf16x8*>(&bs_c[(wc * 10 + n) * 512 + lane * 8]);   \
    STAGE_B(w2, bnx);                                                                       \
    LOADSET(w2, LI, LA, LY);                                                                \
    __builtin_amdgcn_s_barrier();                                                           \
    __builtin_amdgcn_s_setprio(1);                                                          \
    _Pragma("unroll")                                                                       \
    for (int n = 0; n < 5; ++n) {                                                           \
        acc[0][n] = MFMA(af0, bfv[n], acc[0][n]);                                           \
        acc[1][n] = MFMA(af1, bfv[n], acc[1][n]);                                           \
    }                                                                                       \
    __builtin_amdgcn_s_setprio(0);                                                          \
    __builtin_amdgcn_s_barrier();                                                           \
    /* phase 2 */                                                                           \
    _Pragma("unroll")                                                                       \
    for (int n = 5; n < 10; ++n)                                                            \
        bfv[n] = *reinterpret_cast<const bf16x8*>(&bs_c[(wc * 10 + n) * 512 + lane * 8]);   \
    GATE();   /* retire t+1's L+B; keep t+2's */                                            \
    *reinterpret_cast<uint4*>(&As[(tt + 1) & 1][wid * 512 + lane * 8]) = XF(WI, WA, WY);    \
    asm volatile("s_waitcnt lgkmcnt(0)" ::: "memory");                                      \
    __builtin_amdgcn_s_barrier();                                                           \
    __builtin_amdgcn_s_setprio(1);                                                          \
    _Pragma("unroll")                                                                       \
    for (int n = 5; n < 10; ++n) {                                                          \
        acc[0][n] = MFMA(af0, bfv[n], acc[0][n]);                                           \
        acc[1][n] = MFMA(af1, bfv[n], acc[1][n]);                                           \
    }                                                                                       \
    __builtin_amdgcn_s_setprio(0);                                                          \
    __builtin_amdgcn_s_barrier();                                                           \
    ++tt; bcur = (bcur == 2) ? 0 : bcur + 1;                                                \
} while (0)

    while (tt + 1 < NT) {
        STEP(Xi, Xa, Xy, Yi, Ya, Yy);
        STEP(Yi, Ya, Yy, Xi, Xa, Xy);
    }
    if (tt < NT) STEP(Xi, Xa, Xy, Yi, Ya, Yy);
#undef STEP
#undef LOADSET
#undef STAGE_B
#undef XF
#undef GATE

    #pragma unroll
    for (int m = 0; m < 2; ++m) {
        #pragma unroll
        for (int r = 0; r < 4; ++r) {
            const int row = m0 + wr * 32 + m * 16 + fh * 4 + r;
            if (row >= M) continue;
            #pragma unroll
            for (int n = 0; n < 10; ++n) {
                const int col = wc * 160 + n * 16 + fl;
                if (col >= HIDDEN) continue;
                out0[(size_t)row * ldo0 + col] = f2bu(acc[m][n][r]);
            }
        }
    }
}

// ---- weight -> staged panel layout [NT32][20][512] with optional K-row remap ----
__global__ __launch_bounds__(256) void wconv_k(const float* __restrict__ W,
                                               int split, int off1, int Ktot, int NT32,
                                               u16* __restrict__ Wp)
{
    const int id = blockIdx.x * 256 + threadIdx.x;
    if (id >= NT32 * BCH * 512) return;
    const int block = id >> 9, rem = id & 511;
    const int l = rem >> 3, e = rem & 7;
    const int c = block % BCH, kt = block / BCH;
    const int col = c * 16 + (l & 15);
    const int k   = kt * 32 + (l >> 4) * 8 + e;
    float v = 0.f;
    if (col < HIDDEN) {
        if (k < split) {
            const int r = k + off1;
            if (r < Ktot) v = W[(size_t)r * HIDDEN + col];
        } else {
            const int r = k - split;
            if (r < off1) v = W[(size_t)r * HIDDEN + col];
        }
    }
    Wp[id] = f2bu(v);
}

// ---- f_bonds f32 -> bf16 padded [200000][160] ----
__global__ __launch_bounds__(256) void fbconv_k(const float* __restrict__ fb, u16* __restrict__ dst)
{
    const int id = blockIdx.x * 256 + threadIdx.x;
    if (id >= N_BONDS * KP_I) return;
    const int r = id / KP_I, k = id - r * KP_I;
    dst[id] = f2bu(k < BOND_FDIM ? fb[(size_t)r * BOND_FDIM + k] : 0.f);
}

// ---- dst[a][:] = sum_j src[a2b[a][j]][:]   (16B chunks, stride LDA) ----
__global__ __launch_bounds__(256) void agg_k(const u16* __restrict__ src,
                                             const int* __restrict__ a2b,
                                             u16* __restrict__ dst)
{
    const int c = blockIdx.x * 256 + threadIdx.x;
    if (c >= N_ATOMS * CPR) return;
    const int a = c / CPR, q = c - a * CPR;
    const int h = q * 8;
    const int* nb = a2b + (size_t)a * MAX_NB;
    float s[8] = {};
    #pragma unroll
    for (int j = 0; j < MAX_NB; ++j) {
        const int r = nb[j];
        union { uint4 u; u16 s[8]; } x;
        x.u = *(const uint4*)(src + (size_t)r * LDA + h);
        #pragma unroll
        for (int e = 0; e < 8; ++e) s[e] += bu2f(x.s[e]);
    }
    union { uint4 u; u16 s[8]; } o;
    #pragma unroll
    for (int e = 0; e < 8; ++e) o.s[e] = f2bu(s[e]);
    *(uint4*)(dst + (size_t)a * LDA + h) = o.u;
}

// ---- msg[b] = relu(inp[b] + aY[b2a[b]] - Y[b2revb[b]])   (16B chunks) ----
__global__ __launch_bounds__(256) void comb_k(const u16* __restrict__ inp,
                                              const u16* __restrict__ aY,
                                              const u16* __restrict__ Y,
                                              const int* __restrict__ b2a,
                                              const int* __restrict__ b2revb,
                                              u16* __restrict__ msg)
{
    const int c = blockIdx.x * 256 + threadIdx.x;
    if (c >= N_BONDS * CPR) return;
    const int b = c / CPR, q = c - b * CPR;
    const int h = q * 8;
    const int ia = b2a[b], ir = b2revb[b];
    union { uint4 u; u16 s[8]; } xi, xa, xy, o;
    xi.u = *(const uint4*)(inp + (size_t)b * LDA + h);
    xa.u = *(const uint4*)(aY + (size_t)ia * LDA + h);
    xy.u = *(const uint4*)(Y + (size_t)ir * LDA + h);
    #pragma unroll
    for (int j = 0; j < 8; ++j)
        o.s[j] = f2bu(fmaxf(bu2f(xi.s[j]) + bu2f(xa.s[j]) - bu2f(xy.s[j]), 0.f));
    *(uint4*)(msg + (size_t)b * LDA + h) = o.u;
}

// ---- fused final agg + concat (REORDERED, stride 448): dst[a][k] =
//      k<300: sum_j msg[a2b[a][j]][k] | k<433: f_atoms[a][k-300] | 0 ----
__global__ __launch_bounds__(256) void aggcat_k(const u16* __restrict__ msg,
                                                const int* __restrict__ a2b,
                                                const float* __restrict__ fa,
                                                u16* __restrict__ dst)
{
    const int id = blockIdx.x * 256 + threadIdx.x;
    if (id >= N_ATOMS * (KP_O / 4)) return;
    const int a = id / (KP_O / 4), c = id - a * (KP_O / 4);
    const int e0 = c * 4;
    union { uint2 u; u16 s[4]; } o;
    if (e0 < HIDDEN) {
        const int* nb = a2b + (size_t)a * MAX_NB;
        float s0 = 0.f, s1 = 0.f, s2 = 0.f, s3 = 0.f;
        #pragma unroll
        for (int j = 0; j < MAX_NB; ++j) {
            union { uint2 u; u16 s[4]; } x;
            x.u = *(const uint2*)(msg + (size_t)nb[j] * LDA + e0);
            s0 += bu2f(x.s[0]); s1 += bu2f(x.s[1]); s2 += bu2f(x.s[2]); s3 += bu2f(x.s[3]);
        }
        o.s[0] = f2bu(s0); o.s[1] = f2bu(s1); o.s[2] = f2bu(s2); o.s[3] = f2bu(s3);
    } else {
        #pragma unroll
        for (int j = 0; j < 4; ++j) {
            const int fi = e0 + j - HIDDEN;
            o.s[j] = (fi >= 0 && fi < ATOM_FDIM) ? f2bu(fa[(size_t)a * ATOM_FDIM + fi]) : (u16)0;
        }
    }
    *(uint2*)(dst + (size_t)a * KP_O + e0) = o.u;
}

// ---- per-mol mean over sorted atom2mol ----
__global__ __launch_bounds__(320) void pool_k(const u16* __restrict__ ah,
                                              const int* __restrict__ a2m,
                                              float* __restrict__ out)
{
    const int m = blockIdx.x;
    int lo, hi;
    { int l = 0, r = N_ATOMS;
      while (l < r) { int mid = (l + r) >> 1; if (a2m[mid] < m) l = mid + 1; else r = mid; }
      lo = l; }
    { int l = lo, r = N_ATOMS;
      while (l < r) { int mid = (l + r) >> 1; if (a2m[mid] < m + 1) l = mid + 1; else r = mid; }
      hi = l; }
    const float inv = 1.0f / (float)((hi - lo) > 1 ? (hi - lo) : 1);
    const int h = threadIdx.x;
    if (h >= HIDDEN) return;
    float s = 0.f;
    for (int a = lo; a < hi; ++a) s += bu2f(ah[(size_t)a * LDA + h]);
    out[(size_t)m * HIDDEN + h] = s * inv;
}

extern "C" void kernel_launch(void* const* d_in, const int* in_sizes, int n_in,
                              void* d_out, int out_size, void* d_ws, size_t ws_size,
                              hipStream_t stream)
{
    const float* f_atoms  = (const float*)d_in[0];
    const float* f_bonds  = (const float*)d_in[1];
    const int*   a2b      = (const int*)d_in[2];
    const int*   b2a      = (const int*)d_in[3];
    const int*   b2revb   = (const int*)d_in[4];
    const int*   atom2mol = (const int*)d_in[5];
    const float* W_i      = (const float*)d_in[6];
    const float* W_h      = (const float*)d_in[7];
    const float* W_o_w    = (const float*)d_in[8];
    const float* W_o_b    = (const float*)d_in[9];
    float* out = (float*)d_out;

    // ---- workspace (bf16 as u16); +TM rows slack per big buffer ----
    char* p = (char*)d_ws;
    auto alloc = [&](size_t bytes) { char* r = p; p += (bytes + 255) & ~(size_t)255; return r; };
    u16* B0 = (u16*)alloc(((size_t)N_BONDS + TM) * LDA * 2);   // inp -> ah
    u16* B1 = (u16*)alloc(((size_t)N_BONDS + TM) * LDA * 2);   // fb16 -> Y1 -> msg2
    u16* B2 = (u16*)alloc(((size_t)N_BONDS + TM) * LDA * 2);   // Y2 -> concat
    u16* aY = (u16*)alloc(((size_t)N_ATOMS + TM) * LDA * 2);
    u16* Wpi = (u16*)alloc((size_t)(KP_I / 32) * BCH * 512 * 2);
    u16* Wph = (u16*)alloc((size_t)(KP_H / 32) * BCH * 512 * 2);
    u16* Wpo = (u16*)alloc((size_t)(KP_O / 32) * BCH * 512 * 2);
    if ((size_t)(p - (char*)d_ws) > ws_size) return;

    u16* inp    = B0;
    u16* fb16   = B1;   // [200000][160], dead after mm0
    u16* Y1     = B1;   // after fb16 dead
    u16* Y2     = B2;
    u16* msg2   = B1;   // Y1 dead after AM2 GEMM
    u16* concat = B2;   // [100000][448]; Y2 dead after comb
    u16* ah     = B0;   // inp dead after comb

    const dim3 blk(256);
    auto g1 = [](long long n) { return dim3((unsigned)((n + 255) / 256)); };
    const dim3 blkG(1024);
    const dim3 gB((N_BONDS + TM - 1) / TM);   // 782
    const dim3 gA((N_ATOMS + TM - 1) / TM);   // 391

    const int BIGSPLIT = 1 << 20;
    wconv_k<<<g1((long long)(KP_I / 32) * BCH * 512), blk, 0, stream>>>(
        W_i, BIGSPLIT, 0, BOND_FDIM, KP_I / 32, Wpi);
    wconv_k<<<g1((long long)(KP_H / 32) * BCH * 512), blk, 0, stream>>>(
        W_h, BIGSPLIT, 0, HIDDEN, KP_H / 32, Wph);
    wconv_k<<<g1((long long)(KP_O / 32) * BCH * 512), blk, 0, stream>>>(
        W_o_w, HIDDEN, ATOM_FDIM, ATOM_FDIM + HIDDEN, KP_O / 32, Wpo);
    fbconv_k<<<g1((long long)N_BONDS * KP_I), blk, 0, stream>>>(f_bonds, fb16);

    // inp = f_bonds @ W_i (raw; relu fused into AM1's A-stage)  [dense path]
    mm_k<1><<<gB, blkG, 0, stream>>>(fb16, KP_I, Wpi, nullptr,
                                     inp, LDA, N_BONDS, KP_I / 32);

    // iter 1: Y1 = relu(inp) @ W_h   [fused]
    mmf_k<1><<<gB, blkG, 0, stream>>>(inp, LDA, nullptr, nullptr, nullptr, nullptr,
                                      Wph, Y1, LDA, N_BONDS, KP_H / 32);
    agg_k<<<g1((long long)N_ATOMS * CPR), blk, 0, stream>>>(Y1, a2b, aY);

    // iter 2: Y2 = relu(inp + aY[b2a] - Y1[b2revb]) @ W_h   [fused]
    mmf_k<2><<<gB, blkG, 0, stream>>>(inp, LDA, aY, Y1, b2a, b2revb,
                                      Wph, Y2, LDA, N_BONDS, KP_H / 32);
    agg_k<<<g1((long long)N_ATOMS * CPR), blk, 0, stream>>>(Y2, a2b, aY);

    // msg2 materialized (feeds the 6-way aggcat gather)
    comb_k<<<g1((long long)N_BONDS * CPR), blk, 0, stream>>>(inp, aY, Y2, b2a, b2revb, msg2);
    aggcat_k<<<g1((long long)N_ATOMS * (KP_O / 4)), blk, 0, stream>>>(msg2, a2b, f_atoms, concat);

    // output GEMM  [dense path]
    mm_k<2><<<gA, blkG, 0, stream>>>(concat, KP_O, Wpo, W_o_b,
                                     ah, LDA, N_ATOMS, KP_O / 32);
    pool_k<<<dim3(N_MOLS), dim3(320), 0, stream>>>(ah, atom2mol, out);
}

// Round 17
// 1137.511 us; speedup vs baseline: 1.0007x; 1.0007x over previous
//
#include <hip/hip_runtime.h>
#include <stdint.h>

#define ATOM_FDIM 133
#define BOND_FDIM 147
#define HIDDEN    300
#define N_ATOMS   100000
#define N_BONDS   200000
#define MAX_NB    6
#define N_MOLS    4000

#define KP_I 160      // padded K for W_i GEMM (147)
#define KP_H 320      // padded K for W_h GEMM (300)
#define KP_O 448      // padded K for output GEMM (433, reordered amsg|f_atoms|0)
#define LDA  304      // activation row stride in elems (608B, 16B-aligned)
#define CPR  38       // uint4 chunks per activation row (304/8)

#define TM   256      // GEMM tile rows (16 waves x 16 rows)
#define BCH  20       // B chunks (1KB) per K32 tile (NPAD = 320)

typedef unsigned short u16;
typedef short bf16x8 __attribute__((ext_vector_type(8)));
typedef float f32x4 __attribute__((ext_vector_type(4)));

__device__ __forceinline__ u16 f2bu(float f) {            // f32 -> bf16 (RNE)
    unsigned u = __float_as_uint(f);
    u += 0x7FFFu + ((u >> 16) & 1u);
    return (u16)(u >> 16);
}
__device__ __forceinline__ float bu2f(u16 b) { return __uint_as_float(((unsigned)b) << 16); }

__device__ __forceinline__ uint4 relu_bf16x8(uint4 v) {
    union { uint4 u; u16 s[8]; } x, o;
    x.u = v;
    #pragma unroll
    for (int e = 0; e < 8; ++e) o.s[e] = (x.s[e] & 0x8000u) ? (u16)0 : x.s[e];
    return o.u;
}
__device__ __forceinline__ uint4 comb_bf16x8(uint4 vi, uint4 va, uint4 vy) {
    union { uint4 u; u16 s[8]; } xi, xa, xy, o;
    xi.u = vi; xa.u = va; xy.u = vy;
    #pragma unroll
    for (int e = 0; e < 8; ++e)
        o.s[e] = f2bu(fmaxf(bu2f(xi.s[e]) + bu2f(xa.s[e]) - bu2f(xy.s[e]), 0.f));
    return o.u;
}

#define AS1 __attribute__((address_space(1)))
#define AS3 __attribute__((address_space(3)))
__device__ __forceinline__ void gl_lds(const void* g, void* l) {
    __builtin_amdgcn_global_load_lds((const AS1 void*)g, (AS3 void*)l, 16, 0, 0);
}
#define MFMA(a, b, c) __builtin_amdgcn_mfma_f32_16x16x32_bf16((a), (b), (c), 0, 0, 0)

// ---------- dense-A bf16 MFMA GEMM: 1024 threads, 16 waves, 256x320 tile ----------
// __launch_bounds__(1024, 1): 4 waves/SIMD -> VGPR cap 128 (r16 bug: bare
// (1024) let the compiler pick 8/EU -> 64-VGPR cap -> acc spilled, 1.7GB/dispatch).
// 16 waves as 8x2; wave = 32 rows x 160 cols = 2x10 frags of 16x16x32.
// LDS: A tri 3x16KB + B tri 3x20KB = 108KB -> 16 waves/CU. Stage t+2; gates
// wave-uniform literal (wid<4: vmcnt(3), else vmcnt(2)) retire t+1 only.
// EPI 1: raw | 2: relu(v+bias)
template <int EPI>
__global__ __launch_bounds__(1024, 1) void mm_k(
    const u16* __restrict__ A, int lda,
    const u16* __restrict__ Wp,          // panel layout: [NT][BCH][512]
    const float* __restrict__ bias,
    u16* __restrict__ out0, int ldo0,
    int M, int NT)                       // NT = Kp/32 >= 3
{
    __shared__ __align__(16) u16 As[3][16 * 512];   // 3 x 16 KB
    __shared__ __align__(16) u16 Bs[3][20 * 512];   // 3 x 20 KB

    const int t    = threadIdx.x;
    const int lane = t & 63, wid = t >> 6;          // wid 0..15
    const int fl   = lane & 15, fh = lane >> 4;
    const int m0   = blockIdx.x * TM;
    const int wr   = wid >> 1, wc = wid & 1;

    int arow = m0 + wid * 16 + fl;
    if (arow > M - 1) arow = M - 1;
    const char* srcAp = (const char*)A + (size_t)arow * (size_t)lda * 2u + (size_t)(fh * 16);
    const char* WpC = (const char*)Wp;
    const size_t srcB0 = (size_t)wid * 1024u + (size_t)lane * 16u;
    const size_t srcB1 = (size_t)(16 + wid) * 1024u + (size_t)lane * 16u;

    f32x4 acc[2][10] = {};

#define STAGE_T(kt, buf) do {                                                      \
        const size_t kb_ = (size_t)(kt) * (size_t)(BCH * 1024);                    \
        gl_lds(srcAp + (size_t)(kt) * 64u, (char*)As[buf] + wid * 1024);           \
        gl_lds(WpC + kb_ + srcB0, (char*)Bs[buf] + wid * 1024);                    \
        if (wid < 4)                                                               \
            gl_lds(WpC + kb_ + srcB1, (char*)Bs[buf] + (16 + wid) * 1024);         \
    } while (0)

#define GATE() do {                                                        \
        if (wid < 4) asm volatile("s_waitcnt vmcnt(3)" ::: "memory");      \
        else         asm volatile("s_waitcnt vmcnt(2)" ::: "memory");      \
    } while (0)

    STAGE_T(0, 0);
    STAGE_T(1, 1);
    GATE();
    __builtin_amdgcn_s_barrier();

    int cur = 0;
    for (int tt = 0; tt < NT; ++tt) {
        int w2 = tt + 2; if (w2 >= NT) w2 -= NT;
        const int nx1 = (cur < 2) ? cur + 1 : 0;
        const int nx2 = (nx1 < 2) ? nx1 + 1 : 0;
        const u16* as_c = As[cur];
        const u16* bs_c = Bs[cur];

        bf16x8 af0, af1, bfv[10];
        // ---------- phase 1 ----------
        af0 = *reinterpret_cast<const bf16x8*>(&as_c[(wr * 2 + 0) * 512 + lane * 8]);
        af1 = *reinterpret_cast<const bf16x8*>(&as_c[(wr * 2 + 1) * 512 + lane * 8]);
        #pragma unroll
        for (int n = 0; n < 5; ++n)
            bfv[n] = *reinterpret_cast<const bf16x8*>(&bs_c[(wc * 10 + n) * 512 + lane * 8]);
        STAGE_T(w2, nx2);
        __builtin_amdgcn_s_barrier();
        __builtin_amdgcn_s_setprio(1);
        #pragma unroll
        for (int n = 0; n < 5; ++n) {
            acc[0][n] = MFMA(af0, bfv[n], acc[0][n]);
            acc[1][n] = MFMA(af1, bfv[n], acc[1][n]);
        }
        __builtin_amdgcn_s_setprio(0);
        __builtin_amdgcn_s_barrier();

        // ---------- phase 2 ----------
        #pragma unroll
        for (int n = 5; n < 10; ++n)
            bfv[n] = *reinterpret_cast<const bf16x8*>(&bs_c[(wc * 10 + n) * 512 + lane * 8]);
        GATE();                                   // retire tile t+1's stages only
        __builtin_amdgcn_s_barrier();
        __builtin_amdgcn_s_setprio(1);
        #pragma unroll
        for (int n = 5; n < 10; ++n) {
            acc[0][n] = MFMA(af0, bfv[n], acc[0][n]);
            acc[1][n] = MFMA(af1, bfv[n], acc[1][n]);
        }
        __builtin_amdgcn_s_setprio(0);
        __builtin_amdgcn_s_barrier();
        cur = nx1;
    }
#undef STAGE_T
#undef GATE

    #pragma unroll
    for (int m = 0; m < 2; ++m) {
        #pragma unroll
        for (int r = 0; r < 4; ++r) {
            const int row = m0 + wr * 32 + m * 16 + fh * 4 + r;
            if (row >= M) continue;
            #pragma unroll
            for (int n = 0; n < 10; ++n) {
                const int col = wc * 160 + n * 16 + fl;
                if (col >= HIDDEN) continue;
                const float v = acc[m][n][r];
                if (EPI == 1) out0[(size_t)row * ldo0 + col] = f2bu(v);
                else          out0[(size_t)row * ldo0 + col] = f2bu(fmaxf(v + bias[col], 0.f));
            }
        }
    }
}

// ---------- fused-A bf16 MFMA GEMM: 1024 threads, 16 waves, reg-staged A ----------
// __launch_bounds__(1024, 1): VGPR cap 128 (r16 spill fix).
// AM1: A' = relu(inp) | AM2: A' = relu(inp + aY[b2a] - Y[b2revb]). Raw out.
// LDS: A dbuf 2x16KB + B tri 3x20KB = 92KB. Per tile each lane loads 1-3 uint4
// (t+2), transforms + 1 ds_write (t+1) after the counted gate. B staged t+2 via
// gl_lds (rotation). Gates: AM1 wid<4 vmcnt(3)/else 2; AM2 5/4. Never drains.
template <int AM>
__global__ __launch_bounds__(1024, 1) void mmf_k(
    const u16* __restrict__ A, int lda,          // inp
    const u16* __restrict__ aYp,                 // AM2
    const u16* __restrict__ Yp,                  // AM2
    const int* __restrict__ b2a,                 // AM2
    const int* __restrict__ b2revb,              // AM2
    const u16* __restrict__ Wp,
    u16* __restrict__ out0, int ldo0,
    int M, int NT)                               // NT = Kp/32 >= 2
{
    __shared__ __align__(16) u16 As[2][16 * 512];   // 2 x 16 KB
    __shared__ __align__(16) u16 Bs[3][20 * 512];   // 3 x 20 KB

    const int t    = threadIdx.x;
    const int lane = t & 63, wid = t >> 6;
    const int fl   = lane & 15, fh = lane >> 4;
    const int m0   = blockIdx.x * TM;
    const int wr   = wid >> 1, wc = wid & 1;

    int arow = m0 + wid * 16 + fl;
    if (arow > M - 1) arow = M - 1;
    const char* pI = (const char*)A + (size_t)arow * (size_t)lda * 2u + (size_t)(fh * 16);
    const char* pA = nullptr; const char* pY = nullptr;
    if constexpr (AM == 2) {
        const int ia = b2a[arow], ir = b2revb[arow];
        pA = (const char*)aYp + (size_t)ia * (LDA * 2) + (size_t)(fh * 16);
        pY = (const char*)Yp  + (size_t)ir * (LDA * 2) + (size_t)(fh * 16);
    }
    const char* WpC = (const char*)Wp;
    const size_t srcB0 = (size_t)wid * 1024u + (size_t)lane * 16u;
    const size_t srcB1 = (size_t)(16 + wid) * 1024u + (size_t)lane * 16u;

    f32x4 acc[2][10] = {};
    uint4 Xi, Xa, Xy, Yi, Ya, Yy;
    (void)Xa; (void)Xy; (void)Ya; (void)Yy;

#define STAGE_B(kt, buf) do {                                                      \
        const size_t kb_ = (size_t)(kt) * (size_t)(BCH * 1024);                    \
        gl_lds(WpC + kb_ + srcB0, (char*)Bs[buf] + wid * 1024);                    \
        if (wid < 4)                                                               \
            gl_lds(WpC + kb_ + srcB1, (char*)Bs[buf] + (16 + wid) * 1024);         \
    } while (0)
#define LOADSET(kt, I0, A0, Y0) do {                                               \
        const size_t kb_ = (size_t)(kt) * 64u;                                     \
        I0 = *reinterpret_cast<const uint4*>(pI + kb_);                            \
        if constexpr (AM == 2) {                                                   \
            A0 = *reinterpret_cast<const uint4*>(pA + kb_);                        \
            Y0 = *reinterpret_cast<const uint4*>(pY + kb_);                        \
        }                                                                          \
    } while (0)
#define XF(I, Aa, Yy) (AM == 2 ? comb_bf16x8(I, Aa, Yy) : relu_bf16x8(I))
#define GATE() do {                                                        \
    if constexpr (AM == 2) {                                               \
        if (wid < 4) asm volatile("s_waitcnt vmcnt(5)" ::: "memory");      \
        else         asm volatile("s_waitcnt vmcnt(4)" ::: "memory");      \
    } else {                                                               \
        if (wid < 4) asm volatile("s_waitcnt vmcnt(3)" ::: "memory");      \
        else         asm volatile("s_waitcnt vmcnt(2)" ::: "memory");      \
    } } while (0)

    // ---- prologue: X<-L(0); B(0); Y<-L(1); B(1); wait X; write A(0); wait B(0) ----
    LOADSET(0, Xi, Xa, Xy);
    STAGE_B(0, 0);
    LOADSET(1, Yi, Ya, Yy);
    STAGE_B(1, 1);
    if constexpr (AM == 2) {
        if (wid < 4) asm volatile("s_waitcnt vmcnt(7)" ::: "memory");
        else         asm volatile("s_waitcnt vmcnt(5)" ::: "memory");
    } else {
        if (wid < 4) asm volatile("s_waitcnt vmcnt(5)" ::: "memory");
        else         asm volatile("s_waitcnt vmcnt(3)" ::: "memory");
    }
    *reinterpret_cast<uint4*>(&As[0][wid * 512 + lane * 8]) = XF(Xi, Xa, Xy);
    GATE();   // B(0) landed; keep L(1)+B(1)
    asm volatile("s_waitcnt lgkmcnt(0)" ::: "memory");
    __builtin_amdgcn_s_barrier();

    int tt = 0, bcur = 0;

#define STEP(LI, LA, LY, WI, WA, WY) do {                                                   \
    int w2 = tt + 2; if (w2 >= NT) w2 -= NT;                                                \
    const u16* as_c = As[tt & 1];                                                           \
    const u16* bs_c = Bs[bcur];                                                             \
    int bnx = bcur + 2; if (bnx >= 3) bnx -= 3;                                             \
    bf16x8 af0, af1, bfv[10];                                                               \
    /* phase 1 */                                                                           \
    af0 = *reinterpret_cast<const bf16x8*>(&as_c[(wr * 2 + 0) * 512 + lane * 8]);           \
    af1 = *reinterpret_cast<const bf16x8*>(&as_c[(wr * 2 + 1) * 512 + lane * 8]);           \
    _Pragma("unroll")                                                                       \
    for (int n = 0; n < 5; ++n)                                                             \
        bfv[n] = *reinterpret_cast<const bf16x8*>(&bs_c[(wc * 10 + n) * 512 + lane * 8]);   \
    STAGE_B(w2, bnx);                                                                       \
    LOADSET(w2, LI, LA, LY);                                                                \
    __builtin_amdgcn_s_barrier();                                                           \
    __builtin_amdgcn_s_setprio(1);                                                          \
    _Pragma("unroll")                                                                       \
    for (int n = 0; n < 5; ++n) {                                                           \
        acc[0][n] = MFMA(af0, bfv[n], acc[0][n]);                                           \
        acc[1][n] = MFMA(af1, bfv[n], acc[1][n]);                                           \
    }                                                                                       \
    __builtin_amdgcn_s_setprio(0);                                                          \
    __builtin_amdgcn_s_barrier();                                                           \
    /* phase 2 */                                                                           \
    _Pragma("unroll")                                                                       \
    for (int n = 5; n < 10; ++n)                                                            \
        bfv[n] = *reinterpret_cast<const bf16x8*>(&bs_c[(wc * 10 + n) * 512 + lane * 8]);   \
    GATE();   /* retire t+1's L+B; keep t+2's */                                            \
    *reinterpret_cast<uint4*>(&As[(tt + 1) & 1][wid * 512 + lane * 8]) = XF(WI, WA, WY);    \
    asm volatile("s_waitcnt lgkmcnt(0)" ::: "memory");                                      \
    __builtin_amdgcn_s_barrier();                                                           \
    __builtin_amdgcn_s_setprio(1);                                                          \
    _Pragma("unroll")                                                                       \
    for (int n = 5; n < 10; ++n) {                                                          \
        acc[0][n] = MFMA(af0, bfv[n], acc[0][n]);                                           \
        acc[1][n] = MFMA(af1, bfv[n], acc[1][n]);                                           \
    }                                                                                       \
    __builtin_amdgcn_s_setprio(0);                                                          \
    __builtin_amdgcn_s_barrier();                                                           \
    ++tt; bcur = (bcur == 2) ? 0 : bcur + 1;                                                \
} while (0)

    while (tt + 1 < NT) {
        STEP(Xi, Xa, Xy, Yi, Ya, Yy);
        STEP(Yi, Ya, Yy, Xi, Xa, Xy);
    }
    if (tt < NT) STEP(Xi, Xa, Xy, Yi, Ya, Yy);
#undef STEP
#undef LOADSET
#undef STAGE_B
#undef XF
#undef GATE

    #pragma unroll
    for (int m = 0; m < 2; ++m) {
        #pragma unroll
        for (int r = 0; r < 4; ++r) {
            const int row = m0 + wr * 32 + m * 16 + fh * 4 + r;
            if (row >= M) continue;
            #pragma unroll
            for (int n = 0; n < 10; ++n) {
                const int col = wc * 160 + n * 16 + fl;
                if (col >= HIDDEN) continue;
                out0[(size_t)row * ldo0 + col] = f2bu(acc[m][n][r]);
            }
        }
    }
}

// ---- weight -> staged panel layout [NT32][20][512] with optional K-row remap ----
__global__ __launch_bounds__(256) void wconv_k(const float* __restrict__ W,
                                               int split, int off1, int Ktot, int NT32,
                                               u16* __restrict__ Wp)
{
    const int id = blockIdx.x * 256 + threadIdx.x;
    if (id >= NT32 * BCH * 512) return;
    const int block = id >> 9, rem = id & 511;
    const int l = rem >> 3, e = rem & 7;
    const int c = block % BCH, kt = block / BCH;
    const int col = c * 16 + (l & 15);
    const int k   = kt * 32 + (l >> 4) * 8 + e;
    float v = 0.f;
    if (col < HIDDEN) {
        if (k < split) {
            const int r = k + off1;
            if (r < Ktot) v = W[(size_t)r * HIDDEN + col];
        } else {
            const int r = k - split;
            if (r < off1) v = W[(size_t)r * HIDDEN + col];
        }
    }
    Wp[id] = f2bu(v);
}

// ---- f_bonds f32 -> bf16 padded [200000][160] ----
__global__ __launch_bounds__(256) void fbconv_k(const float* __restrict__ fb, u16* __restrict__ dst)
{
    const int id = blockIdx.x * 256 + threadIdx.x;
    if (id >= N_BONDS * KP_I) return;
    const int r = id / KP_I, k = id - r * KP_I;
    dst[id] = f2bu(k < BOND_FDIM ? fb[(size_t)r * BOND_FDIM + k] : 0.f);
}

// ---- dst[a][:] = sum_j src[a2b[a][j]][:]   (16B chunks, stride LDA) ----
__global__ __launch_bounds__(256) void agg_k(const u16* __restrict__ src,
                                             const int* __restrict__ a2b,
                                             u16* __restrict__ dst)
{
    const int c = blockIdx.x * 256 + threadIdx.x;
    if (c >= N_ATOMS * CPR) return;
    const int a = c / CPR, q = c - a * CPR;
    const int h = q * 8;
    const int* nb = a2b + (size_t)a * MAX_NB;
    float s[8] = {};
    #pragma unroll
    for (int j = 0; j < MAX_NB; ++j) {
        const int r = nb[j];
        union { uint4 u; u16 s[8]; } x;
        x.u = *(const uint4*)(src + (size_t)r * LDA + h);
        #pragma unroll
        for (int e = 0; e < 8; ++e) s[e] += bu2f(x.s[e]);
    }
    union { uint4 u; u16 s[8]; } o;
    #pragma unroll
    for (int e = 0; e < 8; ++e) o.s[e] = f2bu(s[e]);
    *(uint4*)(dst + (size_t)a * LDA + h) = o.u;
}

// ---- msg[b] = relu(inp[b] + aY[b2a[b]] - Y[b2revb[b]])   (16B chunks) ----
__global__ __launch_bounds__(256) void comb_k(const u16* __restrict__ inp,
                                              const u16* __restrict__ aY,
                                              const u16* __restrict__ Y,
                                              const int* __restrict__ b2a,
                                              const int* __restrict__ b2revb,
                                              u16* __restrict__ msg)
{
    const int c = blockIdx.x * 256 + threadIdx.x;
    if (c >= N_BONDS * CPR) return;
    const int b = c / CPR, q = c - b * CPR;
    const int h = q * 8;
    const int ia = b2a[b], ir = b2revb[b];
    union { uint4 u; u16 s[8]; } xi, xa, xy, o;
    xi.u = *(const uint4*)(inp + (size_t)b * LDA + h);
    xa.u = *(const uint4*)(aY + (size_t)ia * LDA + h);
    xy.u = *(const uint4*)(Y + (size_t)ir * LDA + h);
    #pragma unroll
    for (int j = 0; j < 8; ++j)
        o.s[j] = f2bu(fmaxf(bu2f(xi.s[j]) + bu2f(xa.s[j]) - bu2f(xy.s[j]), 0.f));
    *(uint4*)(msg + (size_t)b * LDA + h) = o.u;
}

// ---- fused final agg + concat (REORDERED, stride 448): dst[a][k] =
//      k<300: sum_j msg[a2b[a][j]][k] | k<433: f_atoms[a][k-300] | 0 ----
__global__ __launch_bounds__(256) void aggcat_k(const u16* __restrict__ msg,
                                                const int* __restrict__ a2b,
                                                const float* __restrict__ fa,
                                                u16* __restrict__ dst)
{
    const int id = blockIdx.x * 256 + threadIdx.x;
    if (id >= N_ATOMS * (KP_O / 4)) return;
    const int a = id / (KP_O / 4), c = id - a * (KP_O / 4);
    const int e0 = c * 4;
    union { uint2 u; u16 s[4]; } o;
    if (e0 < HIDDEN) {
        const int* nb = a2b + (size_t)a * MAX_NB;
        float s0 = 0.f, s1 = 0.f, s2 = 0.f, s3 = 0.f;
        #pragma unroll
        for (int j = 0; j < MAX_NB; ++j) {
            union { uint2 u; u16 s[4]; } x;
            x.u = *(const uint2*)(msg + (size_t)nb[j] * LDA + e0);
            s0 += bu2f(x.s[0]); s1 += bu2f(x.s[1]); s2 += bu2f(x.s[2]); s3 += bu2f(x.s[3]);
        }
        o.s[0] = f2bu(s0); o.s[1] = f2bu(s1); o.s[2] = f2bu(s2); o.s[3] = f2bu(s3);
    } else {
        #pragma unroll
        for (int j = 0; j < 4; ++j) {
            const int fi = e0 + j - HIDDEN;
            o.s[j] = (fi >= 0 && fi < ATOM_FDIM) ? f2bu(fa[(size_t)a * ATOM_FDIM + fi]) : (u16)0;
        }
    }
    *(uint2*)(dst + (size_t)a * KP_O + e0) = o.u;
}

// ---- per-mol mean over sorted atom2mol ----
__global__ __launch_bounds__(320) void pool_k(const u16* __restrict__ ah,
                                              const int* __restrict__ a2m,
                                              float* __restrict__ out)
{
    const int m = blockIdx.x;
    int lo, hi;
    { int l = 0, r = N_ATOMS;
      while (l < r) { int mid = (l + r) >> 1; if (a2m[mid] < m) l = mid + 1; else r = mid; }
      lo = l; }
    { int l = lo, r = N_ATOMS;
      while (l < r) { int mid = (l + r) >> 1; if (a2m[mid] < m + 1) l = mid + 1; else r = mid; }
      hi = l; }
    const float inv = 1.0f / (float)((hi - lo) > 1 ? (hi - lo) : 1);
    const int h = threadIdx.x;
    if (h >= HIDDEN) return;
    float s = 0.f;
    for (int a = lo; a < hi; ++a) s += bu2f(ah[(size_t)a * LDA + h]);
    out[(size_t)m * HIDDEN + h] = s * inv;
}

extern "C" void kernel_launch(void* const* d_in, const int* in_sizes, int n_in,
                              void* d_out, int out_size, void* d_ws, size_t ws_size,
                              hipStream_t stream)
{
    const float* f_atoms  = (const float*)d_in[0];
    const float* f_bonds  = (const float*)d_in[1];
    const int*   a2b      = (const int*)d_in[2];
    const int*   b2a      = (const int*)d_in[3];
    const int*   b2revb   = (const int*)d_in[4];
    const int*   atom2mol = (const int*)d_in[5];
    const float* W_i      = (const float*)d_in[6];
    const float* W_h      = (const float*)d_in[7];
    const float* W_o_w    = (const float*)d_in[8];
    const float* W_o_b    = (const float*)d_in[9];
    float* out = (float*)d_out;

    // ---- workspace (bf16 as u16); +TM rows slack per big buffer ----
    char* p = (char*)d_ws;
    auto alloc = [&](size_t bytes) { char* r = p; p += (bytes + 255) & ~(size_t)255; return r; };
    u16* B0 = (u16*)alloc(((size_t)N_BONDS + TM) * LDA * 2);   // inp -> ah
    u16* B1 = (u16*)alloc(((size_t)N_BONDS + TM) * LDA * 2);   // fb16 -> Y1 -> msg2
    u16* B2 = (u16*)alloc(((size_t)N_BONDS + TM) * LDA * 2);   // Y2 -> concat
    u16* aY = (u16*)alloc(((size_t)N_ATOMS + TM) * LDA * 2);
    u16* Wpi = (u16*)alloc((size_t)(KP_I / 32) * BCH * 512 * 2);
    u16* Wph = (u16*)alloc((size_t)(KP_H / 32) * BCH * 512 * 2);
    u16* Wpo = (u16*)alloc((size_t)(KP_O / 32) * BCH * 512 * 2);
    if ((size_t)(p - (char*)d_ws) > ws_size) return;

    u16* inp    = B0;
    u16* fb16   = B1;   // [200000][160], dead after mm0
    u16* Y1     = B1;   // after fb16 dead
    u16* Y2     = B2;
    u16* msg2   = B1;   // Y1 dead after AM2 GEMM
    u16* concat = B2;   // [100000][448]; Y2 dead after comb
    u16* ah     = B0;   // inp dead after comb

    const dim3 blk(256);
    auto g1 = [](long long n) { return dim3((unsigned)((n + 255) / 256)); };
    const dim3 blkG(1024);
    const dim3 gB((N_BONDS + TM - 1) / TM);   // 782
    const dim3 gA((N_ATOMS + TM - 1) / TM);   // 391

    const int BIGSPLIT = 1 << 20;
    wconv_k<<<g1((long long)(KP_I / 32) * BCH * 512), blk, 0, stream>>>(
        W_i, BIGSPLIT, 0, BOND_FDIM, KP_I / 32, Wpi);
    wconv_k<<<g1((long long)(KP_H / 32) * BCH * 512), blk, 0, stream>>>(
        W_h, BIGSPLIT, 0, HIDDEN, KP_H / 32, Wph);
    wconv_k<<<g1((long long)(KP_O / 32) * BCH * 512), blk, 0, stream>>>(
        W_o_w, HIDDEN, ATOM_FDIM, ATOM_FDIM + HIDDEN, KP_O / 32, Wpo);
    fbconv_k<<<g1((long long)N_BONDS * KP_I), blk, 0, stream>>>(f_bonds, fb16);

    // inp = f_bonds @ W_i (raw; relu fused into AM1's A-stage)  [dense path]
    mm_k<1><<<gB, blkG, 0, stream>>>(fb16, KP_I, Wpi, nullptr,
                                     inp, LDA, N_BONDS, KP_I / 32);

    // iter 1: Y1 = relu(inp) @ W_h   [fused]
    mmf_k<1><<<gB, blkG, 0, stream>>>(inp, LDA, nullptr, nullptr, nullptr, nullptr,
                                      Wph, Y1, LDA, N_BONDS, KP_H / 32);
    agg_k<<<g1((long long)N_ATOMS * CPR), blk, 0, stream>>>(Y1, a2b, aY);

    // iter 2: Y2 = relu(inp + aY[b2a] - Y1[b2revb]) @ W_h   [fused]
    mmf_k<2><<<gB, blkG, 0, stream>>>(inp, LDA, aY, Y1, b2a, b2revb,
                                      Wph, Y2, LDA, N_BONDS, KP_H / 32);
    agg_k<<<g1((long long)N_ATOMS * CPR), blk, 0, stream>>>(Y2, a2b, aY);

    // msg2 materialized (feeds the 6-way aggcat gather)
    comb_k<<<g1((long long)N_BONDS * CPR), blk, 0, stream>>>(inp, aY, Y2, b2a, b2revb, msg2);
    aggcat_k<<<g1((long long)N_ATOMS * (KP_O / 4)), blk, 0, stream>>>(msg2, a2b, f_atoms, concat);

    // output GEMM  [dense path]
    mm_k<2><<<gA, blkG, 0, stream>>>(concat, KP_O, Wpo, W_o_b,
                                     ah, LDA, N_ATOMS, KP_O / 32);
    pool_k<<<dim3(N_MOLS), dim3(320), 0, stream>>>(ah, atom2mol, out);
}

// Round 18
// 818.997 us; speedup vs baseline: 1.3899x; 1.3889x over previous
//
#include <hip/hip_runtime.h>
#include <stdint.h>

#define ATOM_FDIM 133
#define BOND_FDIM 147
#define HIDDEN    300
#define N_ATOMS   100000
#define N_BONDS   200000
#define MAX_NB    6
#define N_MOLS    4000

#define KP_I 160      // padded K for W_i GEMM (147)
#define KP_H 320      // padded K for W_h GEMM (300); = 5 x 64 for mmf
#define KP_O 448      // padded K for output GEMM (433, reordered amsg|f_atoms|0)
#define LDA  304      // activation row stride in elems (608B, 16B-aligned)
#define CPR  38       // uint4 chunks per activation row (304/8)

#define TM   128      // GEMM tile rows
#define ACH  8        // A chunks (1KB) per K32 tile
#define BCH  20       // B chunks (1KB) per K32 tile (NPAD = 320)

typedef unsigned short u16;
typedef short bf16x8 __attribute__((ext_vector_type(8)));
typedef float f32x4 __attribute__((ext_vector_type(4)));

__device__ __forceinline__ u16 f2bu(float f) {            // f32 -> bf16 (RNE)
    unsigned u = __float_as_uint(f);
    u += 0x7FFFu + ((u >> 16) & 1u);
    return (u16)(u >> 16);
}
__device__ __forceinline__ float bu2f(u16 b) { return __uint_as_float(((unsigned)b) << 16); }

__device__ __forceinline__ uint4 relu_bf16x8(uint4 v) {
    union { uint4 u; u16 s[8]; } x, o;
    x.u = v;
    #pragma unroll
    for (int e = 0; e < 8; ++e) o.s[e] = (x.s[e] & 0x8000u) ? (u16)0 : x.s[e];
    return o.u;
}
__device__ __forceinline__ uint4 comb_bf16x8(uint4 vi, uint4 va, uint4 vy) {
    union { uint4 u; u16 s[8]; } xi, xa, xy, o;
    xi.u = vi; xa.u = va; xy.u = vy;
    #pragma unroll
    for (int e = 0; e < 8; ++e)
        o.s[e] = f2bu(fmaxf(bu2f(xi.s[e]) + bu2f(xa.s[e]) - bu2f(xy.s[e]), 0.f));
    return o.u;
}

#define AS1 __attribute__((address_space(1)))
#define AS3 __attribute__((address_space(3)))
__device__ __forceinline__ void gl_lds(const void* g, void* l) {
    __builtin_amdgcn_global_load_lds((const AS1 void*)g, (AS3 void*)l, 16, 0, 0);
}
#define MFMA(a, b, c) __builtin_amdgcn_mfma_f32_16x16x32_bf16((a), (b), (c), 0, 0, 0)

// ---------- dense-A bf16 MFMA GEMM: gl_lds tri-buffer BK=32 (r12-proven) ----------
// Block: 128 rows x 320 cols, 512 threads (8 waves, 4x2). Wave: 32 rows x 160
// cols = 2x10 frags of 16x16x32. LDS: 3 x (A 8KB + B 20KB) = 84KB.
// A and B staged via global_load_lds 2 tiles ahead; counted gate (wid<4:
// vmcnt(4), else vmcnt(3)) retires only tile t+1's stages. Never drains.
// EPI 1: out0=raw | 2: out0=relu(v+bias)
template <int EPI>
__global__ __launch_bounds__(512, 2) void mm_k(
    const u16* __restrict__ A, int lda,
    const u16* __restrict__ Wp,          // panel layout: [NT32][BCH][512]
    const float* __restrict__ bias,
    u16* __restrict__ out0, int ldo0,
    int M, int NT)                       // NT = Kp/32 >= 3
{
    __shared__ __align__(16) u16 As[3][ACH * 512];   // 3 x 8 KB
    __shared__ __align__(16) u16 Bs[3][BCH * 512];   // 3 x 20 KB

    const int t    = threadIdx.x;
    const int lane = t & 63, wid = t >> 6;
    const int fl   = lane & 15, fh = lane >> 4;
    const int m0   = blockIdx.x * TM;
    const int wr   = wid >> 1, wc = wid & 1;

    int arow = m0 + wid * 16 + fl;
    if (arow > M - 1) arow = M - 1;
    const char* srcAp = (const char*)A + (size_t)arow * (size_t)lda * 2u + (size_t)(fh * 16);
    const char* WpC = (const char*)Wp;
    const int bbase = (wid < 4) ? 3 * wid : 12 + 2 * (wid - 4);
    const size_t srcB0 = (size_t)bbase * 1024u + (size_t)lane * 16u;

    f32x4 acc[2][10] = {};

#define STAGE_T(kt, buf) do {                                                    \
        const size_t kbB_ = (size_t)(kt) * (size_t)(BCH * 1024);                 \
        gl_lds(srcAp + (size_t)(kt) * 64u, (char*)As[buf] + wid * 1024);         \
        gl_lds(WpC + kbB_ + srcB0,        (char*)Bs[buf] + bbase * 1024);        \
        gl_lds(WpC + kbB_ + srcB0 + 1024, (char*)Bs[buf] + bbase * 1024 + 1024); \
        if (wid < 4)                                                             \
            gl_lds(WpC + kbB_ + srcB0 + 2048, (char*)Bs[buf] + bbase * 1024 + 2048); \
    } while (0)

#define GATE() do {                                                        \
        if (wid < 4) asm volatile("s_waitcnt vmcnt(4)" ::: "memory");      \
        else         asm volatile("s_waitcnt vmcnt(3)" ::: "memory");      \
    } while (0)

    STAGE_T(0, 0);
    STAGE_T(1, 1);
    GATE();
    __builtin_amdgcn_s_barrier();

    int cur = 0;
    for (int tt = 0; tt < NT; ++tt) {
        int w2 = tt + 2; if (w2 >= NT) w2 -= NT;
        const int nx1 = (cur < 2) ? cur + 1 : 0;
        const int nx2 = (nx1 < 2) ? nx1 + 1 : 0;
        const u16* as_c = As[cur];
        const u16* bs_c = Bs[cur];
        const size_t kbB = (size_t)w2 * (size_t)(BCH * 1024);

        bf16x8 af0, af1, bfv[10];
        // ---------- phase 1 ----------
        af0 = *reinterpret_cast<const bf16x8*>(&as_c[(wr * 2 + 0) * 512 + lane * 8]);
        af1 = *reinterpret_cast<const bf16x8*>(&as_c[(wr * 2 + 1) * 512 + lane * 8]);
        #pragma unroll
        for (int n = 0; n < 5; ++n)
            bfv[n] = *reinterpret_cast<const bf16x8*>(&bs_c[(wc * 10 + n) * 512 + lane * 8]);
        gl_lds(srcAp + (size_t)w2 * 64u, (char*)As[nx2] + wid * 1024);
        gl_lds(WpC + kbB + srcB0, (char*)Bs[nx2] + bbase * 1024);
        __builtin_amdgcn_s_barrier();
        __builtin_amdgcn_s_setprio(1);
        #pragma unroll
        for (int n = 0; n < 5; ++n) {
            acc[0][n] = MFMA(af0, bfv[n], acc[0][n]);
            acc[1][n] = MFMA(af1, bfv[n], acc[1][n]);
        }
        __builtin_amdgcn_s_setprio(0);
        __builtin_amdgcn_s_barrier();

        // ---------- phase 2 ----------
        #pragma unroll
        for (int n = 5; n < 10; ++n)
            bfv[n] = *reinterpret_cast<const bf16x8*>(&bs_c[(wc * 10 + n) * 512 + lane * 8]);
        gl_lds(WpC + kbB + srcB0 + 1024, (char*)Bs[nx2] + bbase * 1024 + 1024);
        if (wid < 4)
            gl_lds(WpC + kbB + srcB0 + 2048, (char*)Bs[nx2] + bbase * 1024 + 2048);
        GATE();
        __builtin_amdgcn_s_barrier();
        __builtin_amdgcn_s_setprio(1);
        #pragma unroll
        for (int n = 5; n < 10; ++n) {
            acc[0][n] = MFMA(af0, bfv[n], acc[0][n]);
            acc[1][n] = MFMA(af1, bfv[n], acc[1][n]);
        }
        __builtin_amdgcn_s_setprio(0);
        __builtin_amdgcn_s_barrier();
        cur = nx1;
    }
#undef STAGE_T
#undef GATE

    #pragma unroll
    for (int m = 0; m < 2; ++m) {
        #pragma unroll
        for (int r = 0; r < 4; ++r) {
            const int row = m0 + wr * 32 + m * 16 + fh * 4 + r;
            if (row >= M) continue;
            #pragma unroll
            for (int n = 0; n < 10; ++n) {
                const int col = wc * 160 + n * 16 + fl;
                if (col >= HIDDEN) continue;
                const float v = acc[m][n][r];
                if (EPI == 1) out0[(size_t)row * ldo0 + col] = f2bu(v);
                else          out0[(size_t)row * ldo0 + col] = f2bu(fmaxf(v + bias[col], 0.f));
            }
        }
    }
}

// ---------- fused-A bf16 MFMA GEMM, BK=64, reg-staged A (r15-proven, 169us) ----------
// AM1: A' = relu(inp) | AM2: A' = relu(inp + aY[b2a] - Y[b2revb]). Raw out.
// LDS: A dbl 2x16KB + B dbl 2x40KB = 112KB. B staged into Bs[(tt+1)&1]
// (unwrapped parity -- wrap-clobber fix). Gate vmcnt(2)/(6) keeps t+2's L-regs.
template <int AM>
__global__ __launch_bounds__(512, 2) void mmf_k(
    const u16* __restrict__ A, int lda,          // inp
    const u16* __restrict__ aYp,                 // AM2
    const u16* __restrict__ Yp,                  // AM2
    const int* __restrict__ b2a,                 // AM2
    const int* __restrict__ b2revb,              // AM2
    const u16* __restrict__ Wp,
    u16* __restrict__ out0, int ldo0,
    int M, int NT)                               // NT = Kp/64 >= 2
{
    __shared__ __align__(16) u16 As[2][16 * 512];   // 2 x 16 KB
    __shared__ __align__(16) u16 Bs[2][40 * 512];   // 2 x 40 KB

    const int t    = threadIdx.x;
    const int lane = t & 63, wid = t >> 6;
    const int fl   = lane & 15, fh = lane >> 4;
    const int m0   = blockIdx.x * TM;
    const int wr   = wid >> 1, wc = wid & 1;

    int arow = m0 + wid * 16 + fl;
    if (arow > M - 1) arow = M - 1;
    const char* pI = (const char*)A + (size_t)arow * (size_t)lda * 2u + (size_t)(fh * 16);
    const char* pA = nullptr; const char* pY = nullptr;
    if constexpr (AM == 2) {
        const int ia = b2a[arow], ir = b2revb[arow];
        pA = (const char*)aYp + (size_t)ia * (LDA * 2) + (size_t)(fh * 16);
        pY = (const char*)Yp  + (size_t)ir * (LDA * 2) + (size_t)(fh * 16);
    }
    const char* WpC = (const char*)Wp;
    const size_t srcB0 = (size_t)(5 * wid) * 1024u + (size_t)lane * 16u;

    f32x4 acc[2][10] = {};
    uint4 Xi0, Xi1, Xa0, Xa1, Xy0, Xy1;
    uint4 Yi0, Yi1, Ya0, Ya1, Yy0, Yy1;
    (void)Xa0; (void)Xa1; (void)Xy0; (void)Xy1;
    (void)Ya0; (void)Ya1; (void)Yy0; (void)Yy1;

#define STAGE_B(kt, buf) do {                                                      \
        const size_t kb_ = (size_t)(kt) * 40960u;                                  \
        _Pragma("unroll")                                                          \
        for (int j = 0; j < 5; ++j)                                                \
            gl_lds(WpC + kb_ + srcB0 + (size_t)j * 1024,                           \
                   (char*)Bs[buf] + 5 * wid * 1024 + j * 1024);                    \
    } while (0)
#define LOADSET(kt, I0, I1, A0, A1, Y0, Y1) do {                                   \
        const size_t kb_ = (size_t)(kt) * 128u;                                    \
        I0 = *reinterpret_cast<const uint4*>(pI + kb_);                            \
        I1 = *reinterpret_cast<const uint4*>(pI + kb_ + 64);                       \
        if constexpr (AM == 2) {                                                   \
            A0 = *reinterpret_cast<const uint4*>(pA + kb_);                        \
            A1 = *reinterpret_cast<const uint4*>(pA + kb_ + 64);                   \
            Y0 = *reinterpret_cast<const uint4*>(pY + kb_);                        \
            Y1 = *reinterpret_cast<const uint4*>(pY + kb_ + 64);                   \
        }                                                                          \
    } while (0)
#define XF(I, Aa, Yy) (AM == 2 ? comb_bf16x8(I, Aa, Yy) : relu_bf16x8(I))

    // ---- prologue: X(tile0) regs, B(0), Y(tile1) regs; write A(0); wait B(0) ----
    LOADSET(0, Xi0, Xi1, Xa0, Xa1, Xy0, Xy1);
    STAGE_B(0, 0);
    LOADSET(1, Yi0, Yi1, Ya0, Ya1, Yy0, Yy1);
    if constexpr (AM == 2) asm volatile("s_waitcnt vmcnt(11)" ::: "memory");
    else                   asm volatile("s_waitcnt vmcnt(7)"  ::: "memory");
    *reinterpret_cast<uint4*>(&As[0][wid * 512 + lane * 8])       = XF(Xi0, Xa0, Xy0);
    *reinterpret_cast<uint4*>(&As[0][(8 + wid) * 512 + lane * 8]) = XF(Xi1, Xa1, Xy1);
    if constexpr (AM == 2) asm volatile("s_waitcnt vmcnt(6)" ::: "memory");
    else                   asm volatile("s_waitcnt vmcnt(2)" ::: "memory");
    asm volatile("s_waitcnt lgkmcnt(0)" ::: "memory");
    __builtin_amdgcn_s_barrier();

    int tt = 0;

#define STEP(LI0, LI1, LA0, LA1, LY0, LY1, WI0, WI1, WA0, WA1, WY0, WY1) do {               \
    int w1 = tt + 1; if (w1 >= NT) w1 -= NT;                                                \
    int w2 = tt + 2; if (w2 >= NT) w2 -= NT;                                                \
    const u16* as_c = As[tt & 1];                                                           \
    const u16* bs_c = Bs[tt & 1];                                                           \
    bf16x8 af0, af1, bfv[10];                                                               \
    /* phase 1: K-half 0 */                                                                 \
    af0 = *reinterpret_cast<const bf16x8*>(&as_c[(wr * 2 + 0) * 512 + lane * 8]);           \
    af1 = *reinterpret_cast<const bf16x8*>(&as_c[(wr * 2 + 1) * 512 + lane * 8]);           \
    _Pragma("unroll")                                                                       \
    for (int n = 0; n < 10; ++n)                                                            \
        bfv[n] = *reinterpret_cast<const bf16x8*>(&bs_c[(wc * 10 + n) * 512 + lane * 8]);   \
    STAGE_B(w1, (tt + 1) & 1);  /* UNWRAPPED parity */                                      \
    LOADSET(w2, LI0, LI1, LA0, LA1, LY0, LY1);                                              \
    __builtin_amdgcn_s_barrier();                                                           \
    __builtin_amdgcn_s_setprio(1);                                                          \
    _Pragma("unroll")                                                                       \
    for (int n = 0; n < 10; ++n) {                                                          \
        acc[0][n] = MFMA(af0, bfv[n], acc[0][n]);                                           \
        acc[1][n] = MFMA(af1, bfv[n], acc[1][n]);                                           \
    }                                                                                       \
    __builtin_amdgcn_s_setprio(0);                                                          \
    __builtin_amdgcn_s_barrier();                                                           \
    /* phase 2: K-half 1 */                                                                 \
    af0 = *reinterpret_cast<const bf16x8*>(&as_c[(8 + wr * 2 + 0) * 512 + lane * 8]);       \
    af1 = *reinterpret_cast<const bf16x8*>(&as_c[(8 + wr * 2 + 1) * 512 + lane * 8]);       \
    _Pragma("unroll")                                                                       \
    for (int n = 0; n < 10; ++n)                                                            \
        bfv[n] = *reinterpret_cast<const bf16x8*>(&bs_c[(20 + wc * 10 + n) * 512 + lane * 8]); \
    if constexpr (AM == 2) asm volatile("s_waitcnt vmcnt(6)" ::: "memory");                 \
    else                   asm volatile("s_waitcnt vmcnt(2)" ::: "memory");                 \
    *reinterpret_cast<uint4*>(&As[(tt + 1) & 1][wid * 512 + lane * 8])       = XF(WI0, WA0, WY0); \
    *reinterpret_cast<uint4*>(&As[(tt + 1) & 1][(8 + wid) * 512 + lane * 8]) = XF(WI1, WA1, WY1); \
    asm volatile("s_waitcnt lgkmcnt(0)" ::: "memory");                                      \
    __builtin_amdgcn_s_barrier();                                                           \
    __builtin_amdgcn_s_setprio(1);                                                          \
    _Pragma("unroll")                                                                       \
    for (int n = 0; n < 10; ++n) {                                                          \
        acc[0][n] = MFMA(af0, bfv[n], acc[0][n]);                                           \
        acc[1][n] = MFMA(af1, bfv[n], acc[1][n]);                                           \
    }                                                                                       \
    __builtin_amdgcn_s_setprio(0);                                                          \
    __builtin_amdgcn_s_barrier();                                                           \
    ++tt;                                                                                   \
} while (0)

    while (tt + 1 < NT) {
        STEP(Xi0, Xi1, Xa0, Xa1, Xy0, Xy1, Yi0, Yi1, Ya0, Ya1, Yy0, Yy1);
        STEP(Yi0, Yi1, Ya0, Ya1, Yy0, Yy1, Xi0, Xi1, Xa0, Xa1, Xy0, Xy1);
    }
    if (tt < NT) STEP(Xi0, Xi1, Xa0, Xa1, Xy0, Xy1, Yi0, Yi1, Ya0, Ya1, Yy0, Yy1);
#undef STEP
#undef LOADSET
#undef STAGE_B
#undef XF

    #pragma unroll
    for (int m = 0; m < 2; ++m) {
        #pragma unroll
        for (int r = 0; r < 4; ++r) {
            const int row = m0 + wr * 32 + m * 16 + fh * 4 + r;
            if (row >= M) continue;
            #pragma unroll
            for (int n = 0; n < 10; ++n) {
                const int col = wc * 160 + n * 16 + fl;
                if (col >= HIDDEN) continue;
                out0[(size_t)row * ldo0 + col] = f2bu(acc[m][n][r]);
            }
        }
    }
}

// ---- weight -> staged panel layout [NT32][20][512] with optional K-row remap ----
__global__ __launch_bounds__(256) void wconv_k(const float* __restrict__ W,
                                               int split, int off1, int Ktot, int NT32,
                                               u16* __restrict__ Wp)
{
    const int id = blockIdx.x * 256 + threadIdx.x;
    if (id >= NT32 * BCH * 512) return;
    const int block = id >> 9, rem = id & 511;
    const int l = rem >> 3, e = rem & 7;
    const int c = block % BCH, kt = block / BCH;
    const int col = c * 16 + (l & 15);
    const int k   = kt * 32 + (l >> 4) * 8 + e;
    float v = 0.f;
    if (col < HIDDEN) {
        if (k < split) {
            const int r = k + off1;
            if (r < Ktot) v = W[(size_t)r * HIDDEN + col];
        } else {
            const int r = k - split;
            if (r < off1) v = W[(size_t)r * HIDDEN + col];
        }
    }
    Wp[id] = f2bu(v);
}

// ---- f_bonds f32 -> bf16 padded [200000][160] ----
__global__ __launch_bounds__(256) void fbconv_k(const float* __restrict__ fb, u16* __restrict__ dst)
{
    const int id = blockIdx.x * 256 + threadIdx.x;
    if (id >= N_BONDS * KP_I) return;
    const int r = id / KP_I, k = id - r * KP_I;
    dst[id] = f2bu(k < BOND_FDIM ? fb[(size_t)r * BOND_FDIM + k] : 0.f);
}

// ---- dst[a][:] = sum_j src[a2b[a][j]][:]   (16B chunks, stride LDA) ----
__global__ __launch_bounds__(256) void agg_k(const u16* __restrict__ src,
                                             const int* __restrict__ a2b,
                                             u16* __restrict__ dst)
{
    const int c = blockIdx.x * 256 + threadIdx.x;
    if (c >= N_ATOMS * CPR) return;
    const int a = c / CPR, q = c - a * CPR;
    const int h = q * 8;
    const int* nb = a2b + (size_t)a * MAX_NB;
    float s[8] = {};
    #pragma unroll
    for (int j = 0; j < MAX_NB; ++j) {
        const int r = nb[j];
        union { uint4 u; u16 s[8]; } x;
        x.u = *(const uint4*)(src + (size_t)r * LDA + h);
        #pragma unroll
        for (int e = 0; e < 8; ++e) s[e] += bu2f(x.s[e]);
    }
    union { uint4 u; u16 s[8]; } o;
    #pragma unroll
    for (int e = 0; e < 8; ++e) o.s[e] = f2bu(s[e]);
    *(uint4*)(dst + (size_t)a * LDA + h) = o.u;
}

// ---- msg[b] = relu(inp[b] + aY[b2a[b]] - Y[b2revb[b]])   (16B chunks) ----
__global__ __launch_bounds__(256) void comb_k(const u16* __restrict__ inp,
                                              const u16* __restrict__ aY,
                                              const u16* __restrict__ Y,
                                              const int* __restrict__ b2a,
                                              const int* __restrict__ b2revb,
                                              u16* __restrict__ msg)
{
    const int c = blockIdx.x * 256 + threadIdx.x;
    if (c >= N_BONDS * CPR) return;
    const int b = c / CPR, q = c - b * CPR;
    const int h = q * 8;
    const int ia = b2a[b], ir = b2revb[b];
    union { uint4 u; u16 s[8]; } xi, xa, xy, o;
    xi.u = *(const uint4*)(inp + (size_t)b * LDA + h);
    xa.u = *(const uint4*)(aY + (size_t)ia * LDA + h);
    xy.u = *(const uint4*)(Y + (size_t)ir * LDA + h);
    #pragma unroll
    for (int j = 0; j < 8; ++j)
        o.s[j] = f2bu(fmaxf(bu2f(xi.s[j]) + bu2f(xa.s[j]) - bu2f(xy.s[j]), 0.f));
    *(uint4*)(msg + (size_t)b * LDA + h) = o.u;
}

// ---- fused final agg + concat (REORDERED, stride 448): dst[a][k] =
//      k<300: sum_j msg[a2b[a][j]][k] | k<433: f_atoms[a][k-300] | 0 ----
__global__ __launch_bounds__(256) void aggcat_k(const u16* __restrict__ msg,
                                                const int* __restrict__ a2b,
                                                const float* __restrict__ fa,
                                                u16* __restrict__ dst)
{
    const int id = blockIdx.x * 256 + threadIdx.x;
    if (id >= N_ATOMS * (KP_O / 4)) return;
    const int a = id / (KP_O / 4), c = id - a * (KP_O / 4);
    const int e0 = c * 4;
    union { uint2 u; u16 s[4]; } o;
    if (e0 < HIDDEN) {
        const int* nb = a2b + (size_t)a * MAX_NB;
        float s0 = 0.f, s1 = 0.f, s2 = 0.f, s3 = 0.f;
        #pragma unroll
        for (int j = 0; j < MAX_NB; ++j) {
            union { uint2 u; u16 s[4]; } x;
            x.u = *(const uint2*)(msg + (size_t)nb[j] * LDA + e0);
            s0 += bu2f(x.s[0]); s1 += bu2f(x.s[1]); s2 += bu2f(x.s[2]); s3 += bu2f(x.s[3]);
        }
        o.s[0] = f2bu(s0); o.s[1] = f2bu(s1); o.s[2] = f2bu(s2); o.s[3] = f2bu(s3);
    } else {
        #pragma unroll
        for (int j = 0; j < 4; ++j) {
            const int fi = e0 + j - HIDDEN;
            o.s[j] = (fi >= 0 && fi < ATOM_FDIM) ? f2bu(fa[(size_t)a * ATOM_FDIM + fi]) : (u16)0;
        }
    }
    *(uint2*)(dst + (size_t)a * KP_O + e0) = o.u;
}

// ---- per-mol mean over sorted atom2mol ----
__global__ __launch_bounds__(320) void pool_k(const u16* __restrict__ ah,
                                              const int* __restrict__ a2m,
                                              float* __restrict__ out)
{
    const int m = blockIdx.x;
    int lo, hi;
    { int l = 0, r = N_ATOMS;
      while (l < r) { int mid = (l + r) >> 1; if (a2m[mid] < m) l = mid + 1; else r = mid; }
      lo = l; }
    { int l = lo, r = N_ATOMS;
      while (l < r) { int mid = (l + r) >> 1; if (a2m[mid] < m + 1) l = mid + 1; else r = mid; }
      hi = l; }
    const float inv = 1.0f / (float)((hi - lo) > 1 ? (hi - lo) : 1);
    const int h = threadIdx.x;
    if (h >= HIDDEN) return;
    float s = 0.f;
    for (int a = lo; a < hi; ++a) s += bu2f(ah[(size_t)a * LDA + h]);
    out[(size_t)m * HIDDEN + h] = s * inv;
}

extern "C" void kernel_launch(void* const* d_in, const int* in_sizes, int n_in,
                              void* d_out, int out_size, void* d_ws, size_t ws_size,
                              hipStream_t stream)
{
    const float* f_atoms  = (const float*)d_in[0];
    const float* f_bonds  = (const float*)d_in[1];
    const int*   a2b      = (const int*)d_in[2];
    const int*   b2a      = (const int*)d_in[3];
    const int*   b2revb   = (const int*)d_in[4];
    const int*   atom2mol = (const int*)d_in[5];
    const float* W_i      = (const float*)d_in[6];
    const float* W_h      = (const float*)d_in[7];
    const float* W_o_w    = (const float*)d_in[8];
    const float* W_o_b    = (const float*)d_in[9];
    float* out = (float*)d_out;

    // ---- workspace (bf16 as u16); +16 rows slack per big buffer ----
    char* p = (char*)d_ws;
    auto alloc = [&](size_t bytes) { char* r = p; p += (bytes + 255) & ~(size_t)255; return r; };
    u16* B0 = (u16*)alloc(((size_t)N_BONDS + 16) * LDA * 2);   // inp -> ah
    u16* B1 = (u16*)alloc(((size_t)N_BONDS + 16) * LDA * 2);   // fb16 -> Y1 -> msg2
    u16* B2 = (u16*)alloc(((size_t)N_BONDS + 16) * LDA * 2);   // Y2 -> concat
    u16* aY = (u16*)alloc(((size_t)N_ATOMS + 16) * LDA * 2);
    u16* Wpi = (u16*)alloc((size_t)(KP_I / 32) * BCH * 512 * 2);
    u16* Wph = (u16*)alloc((size_t)(KP_H / 32) * BCH * 512 * 2);
    u16* Wpo = (u16*)alloc((size_t)(KP_O / 32) * BCH * 512 * 2);
    if ((size_t)(p - (char*)d_ws) > ws_size) return;

    u16* inp    = B0;
    u16* fb16   = B1;   // [200000][160], dead after mm0
    u16* Y1     = B1;   // after fb16 dead
    u16* Y2     = B2;
    u16* msg2   = B1;   // Y1 dead after AM2 GEMM
    u16* concat = B2;   // [100000][448]; Y2 dead after comb
    u16* ah     = B0;   // inp dead after comb

    const dim3 blk(256);
    auto g1 = [](long long n) { return dim3((unsigned)((n + 255) / 256)); };
    const dim3 blk5(512);
    const dim3 gB((N_BONDS + TM - 1) / TM);   // 1563
    const dim3 gA((N_ATOMS + TM - 1) / TM);   //  782

    const int BIGSPLIT = 1 << 20;
    wconv_k<<<g1((long long)(KP_I / 32) * BCH * 512), blk, 0, stream>>>(
        W_i, BIGSPLIT, 0, BOND_FDIM, KP_I / 32, Wpi);
    wconv_k<<<g1((long long)(KP_H / 32) * BCH * 512), blk, 0, stream>>>(
        W_h, BIGSPLIT, 0, HIDDEN, KP_H / 32, Wph);
    wconv_k<<<g1((long long)(KP_O / 32) * BCH * 512), blk, 0, stream>>>(
        W_o_w, HIDDEN, ATOM_FDIM, ATOM_FDIM + HIDDEN, KP_O / 32, Wpo);
    fbconv_k<<<g1((long long)N_BONDS * KP_I), blk, 0, stream>>>(f_bonds, fb16);

    // inp = f_bonds @ W_i (raw; relu fused into AM1's A-stage)  [dense BK32 path]
    mm_k<1><<<gB, blk5, 0, stream>>>(fb16, KP_I, Wpi, nullptr,
                                     inp, LDA, N_BONDS, KP_I / 32);

    // iter 1: Y1 = relu(inp) @ W_h   [fused BK64]
    mmf_k<1><<<gB, blk5, 0, stream>>>(inp, LDA, nullptr, nullptr, nullptr, nullptr,
                                      Wph, Y1, LDA, N_BONDS, KP_H / 64);
    agg_k<<<g1((long long)N_ATOMS * CPR), blk, 0, stream>>>(Y1, a2b, aY);

    // iter 2: Y2 = relu(inp + aY[b2a] - Y1[b2revb]) @ W_h   [fused BK64]
    mmf_k<2><<<gB, blk5, 0, stream>>>(inp, LDA, aY, Y1, b2a, b2revb,
                                      Wph, Y2, LDA, N_BONDS, KP_H / 64);
    agg_k<<<g1((long long)N_ATOMS * CPR), blk, 0, stream>>>(Y2, a2b, aY);

    // msg2 materialized (feeds the 6-way aggcat gather)
    comb_k<<<g1((long long)N_BONDS * CPR), blk, 0, stream>>>(inp, aY, Y2, b2a, b2revb, msg2);
    aggcat_k<<<g1((long long)N_ATOMS * (KP_O / 4)), blk, 0, stream>>>(msg2, a2b, f_atoms, concat);

    // output GEMM  [dense BK32 path]
    mm_k<2><<<gA, blk5, 0, stream>>>(concat, KP_O, Wpo, W_o_b,
                                     ah, LDA, N_ATOMS, KP_O / 32);
    pool_k<<<dim3(N_MOLS), dim3(320), 0, stream>>>(ah, atom2mol, out);
}